// Round 8
// baseline (206.923 us; speedup 1.0000x reference)
//
#include <hip/hip_runtime.h>
#include <hip/hip_bf16.h>
#include <stdint.h>

// out = quantize(relu(x @ w + b)), x:8192x1024 f32 (fixed-point 2^-16 grid),
// w:1024x1024 f32 (grid), b:1024 zeros.
// 3-limb-product bf16 decomposition: x = xh+xm, w = wh+wl.
//   y ~= xh*wh + xm*wh + xh*wl   (dropped terms ~3e-5 rms << 0.0156 tolerance)
// Virtual K' = 3*1024 = 3072 over A2 = [xh|xm] (8192x2048), Bt2 = [wh|wl]^T.
// GEMM r8: r7 post-mortem showed LDS-BW bound (224 KB/tile @ ~85B/cyc ~= the
// measured 3220 cyc/tile). Fix: B operand DIRECT global->VGPR (per-tile
// distinct B slice = 16 KB, L1-resident; 4-way wave amplification served by
// TCP port, parallel to LDS port). LDS carries A only: 3-deep x 32 KB = 96 KB,
// 96 KB/tile LDS traffic (was 224). One barrier/tile, counted vmcnt(4)
// (never 0 in loop). B regs double-buffered, prefetched 1 tile ahead.
// XOR bank swizzle on A (rule 21 both-sides), bijective XCD swizzle (T1).

typedef __attribute__((ext_vector_type(8))) short short8;
typedef __attribute__((ext_vector_type(4))) float f32x4;
typedef __attribute__((ext_vector_type(8))) unsigned short us8;

template <int N> struct IC { static constexpr int v = N; };

__device__ __forceinline__ unsigned short f32_to_bf16_rne(float f) {
    uint32_t u = __float_as_uint(f);
    uint32_t r = u + 0x7FFFu + ((u >> 16) & 1u);
    return (unsigned short)(r >> 16);
}
__device__ __forceinline__ float bf16_to_f32(unsigned short s) {
    return __uint_as_float(((uint32_t)s) << 16);
}

// ---------------- split x into 2 exact bf16 limbs (8 elem/thread, 16B stores) ----
__global__ __launch_bounds__(256) void split_x_kernel(const float* __restrict__ x,
                                                      unsigned short* __restrict__ A2) {
    int i = blockIdx.x * 256 + threadIdx.x;       // 8-elem index, 1048576 total
    int e = i * 8;
    int row = e >> 10;
    int col = e & 1023;
    float4 v0 = reinterpret_cast<const float4*>(x)[2 * i];
    float4 v1 = reinterpret_cast<const float4*>(x)[2 * i + 1];
    float vv[8] = {v0.x, v0.y, v0.z, v0.w, v1.x, v1.y, v1.z, v1.w};
    us8 h, m;
    unsigned short* hp = (unsigned short*)&h;
    unsigned short* mp = (unsigned short*)&m;
#pragma unroll
    for (int j = 0; j < 8; ++j) {
        float f = vv[j];
        unsigned short hb = f32_to_bf16_rne(f);
        float r1 = f - bf16_to_f32(hb);
        unsigned short mb = f32_to_bf16_rne(r1);
        hp[j] = hb; mp[j] = mb;
    }
    size_t base = (size_t)row * 2048 + col;
    *reinterpret_cast<us8*>(&A2[base])        = h;
    *reinterpret_cast<us8*>(&A2[base + 1024]) = m;
}

// ---------------- transpose + split w into 2 exact bf16 limbs ----------------
__global__ __launch_bounds__(1024) void split_w_kernel(const float* __restrict__ w,
                                                       unsigned short* __restrict__ Bt2) {
    __shared__ float ts[32][33];
    int tx = threadIdx.x, ty = threadIdx.y;
    int n0 = blockIdx.x * 32, k0 = blockIdx.y * 32;
    ts[ty][tx] = w[(size_t)(k0 + ty) * 1024 + (n0 + tx)];
    __syncthreads();
    float f = ts[tx][ty];                      // = w[k0+tx][n0+ty]
    unsigned short h = f32_to_bf16_rne(f);
    float r = f - bf16_to_f32(h);
    unsigned short l = f32_to_bf16_rne(r);
    int n = n0 + ty, k = k0 + tx;
    Bt2[(size_t)n * 2048 + k]        = h;
    Bt2[(size_t)n * 2048 + 1024 + k] = l;
}

// ---------------- GEMM ----------------
#define BM 256
#define BN 128
#define BK 64
#define NT 48   // 3 limb-product blocks x 16 sub-tiles of 64

__device__ __forceinline__ void load16_to_lds(const void* g, void* l) {
    __builtin_amdgcn_global_load_lds(
        (const __attribute__((address_space(1))) unsigned int*)g,
        (__attribute__((address_space(3))) unsigned int*)l,
        16, 0, 0);
}

__device__ __forceinline__ void rd4(short8* dst, const void* base, const int* offs) {
#pragma unroll
    for (int f = 0; f < 4; ++f)
        dst[f] = *reinterpret_cast<const short8*>((const char*)base + offs[f]);
}

__global__ __launch_bounds__(512, 2) void gemm_kernel(const unsigned short* __restrict__ A2,
                                                      const unsigned short* __restrict__ Bt2,
                                                      const float* __restrict__ bias,
                                                      float* __restrict__ out) {
    __shared__ unsigned short As[3][BM * BK];   // 3 x 32 KB = 96 KB (A only)

    const int tid  = threadIdx.x;
    const int lane = tid & 63;
    const int wave = tid >> 6;
    const int wr = wave >> 1, wc = wave & 1;    // 4M x 2N waves, each 64x64 out

    // Bijective XCD swizzle: grid=256, xcd=bid%8 owns bm {4*xcd..4*xcd+3} x all bn
    const int bid = blockIdx.x;
    const int wg  = (bid & 7) * 32 + (bid >> 3);
    const int bm = wg >> 3, bn = wg & 7;
    const int m0 = bm * BM, n0 = bn * BN;

    f32x4 acc[4][4];
#pragma unroll
    for (int i = 0; i < 4; ++i)
#pragma unroll
        for (int j = 0; j < 4; ++j) acc[i][j] = (f32x4)0.0f;

    // ---- hoisted A ds_read byte offsets (buffer-relative) ----
    int a0[4], a1[4];
    {
        const int ch0 = lane >> 4, ch1 = 4 + (lane >> 4);
#pragma unroll
        for (int f = 0; f < 4; ++f) {
            int ar = wr * 64 + f * 16 + (lane & 15);
            a0[f] = ar * 128 + ((ch0 ^ (ar & 7)) << 4);
            a1[f] = ar * 128 + ((ch1 ^ (ar & 7)) << 4);
        }
    }
    // ---- hoisted A stage offsets ----
    int aTh[4];
#pragma unroll
    for (int it = 0; it < 4; ++it) {
        int c = it * 512 + tid, row = c >> 3, sw = (c & 7) ^ (row & 7);
        aTh[it] = (m0 + row) * 2048 + sw * 8;
    }
    const int dst16 = tid * 16;

    // ---- hoisted B direct-load element offsets (frag f: rows f&3, phase f>>2) ----
    int bOff[8];
#pragma unroll
    for (int f = 0; f < 8; ++f) {
        int brow = n0 + wc * 64 + (f & 3) * 16 + (lane & 15);
        int ch   = (f >> 2) * 4 + (lane >> 4);
        bOff[f]  = brow * 2048 + ch * 8;
    }

    // A limb segments over virtual-K blocks [h, m, h]; B segments [wh, wh, wl]
    auto aoff_of = [](int t) { int blk = t >> 4; return ((blk == 1) ? 1024 : 0) + (t & 15) * 64; };
    auto boff_of = [](int t) { int blk = t >> 4; return ((blk == 2) ? 1024 : 0) + (t & 15) * 64; };

    // double-buffered B fragment registers (tile parity picks consume/load)
    short8 bA[8], bB[8];

    // one K-tile: {8 A ds_read | 8 B(t+1) gload->reg | 4 A(t+2) gload_lds}
    //             -> setprio 32 MFMA -> vmcnt(4) -> lgkm(0) -> barrier
    auto tile = [&](auto LBC, auto RBC, int t, bool doA, bool doB) {
        constexpr int LB = decltype(LBC)::v;
        constexpr int NB = (LB + 2) % 3;
        constexpr int RB = decltype(RBC)::v;
        short8 (&bc)[8] = *(RB == 0 ? &bA : &bB);   // consume (loaded at t-1)
        short8 (&bl)[8] = *(RB == 0 ? &bB : &bA);   // load target for t+1
        short8 af0[4], af1[4];
        rd4(af0, As[LB], a0);
        rd4(af1, As[LB], a1);
        if (doB) {
            const unsigned short* bp = Bt2 + boff_of(t + 1);
#pragma unroll
            for (int f = 0; f < 8; ++f)
                bl[f] = *reinterpret_cast<const short8*>(bp + bOff[f]);
        }
        if (doA) {
            const unsigned short* pA_ = A2 + aoff_of(t + 2);
#pragma unroll
            for (int it = 0; it < 4; ++it)
                load16_to_lds(pA_ + aTh[it], (char*)As[NB] + it * 8192 + dst16);
        }
        __builtin_amdgcn_s_setprio(1);
#pragma unroll
        for (int i = 0; i < 4; ++i)
#pragma unroll
            for (int j = 0; j < 4; ++j)
                acc[i][j] = __builtin_amdgcn_mfma_f32_16x16x32_bf16(af0[i], bc[j], acc[i][j], 0, 0, 0);
#pragma unroll
        for (int i = 0; i < 4; ++i)
#pragma unroll
            for (int j = 0; j < 4; ++j)
                acc[i][j] = __builtin_amdgcn_mfma_f32_16x16x32_bf16(af1[i], bc[4 + j], acc[i][j], 0, 0, 0);
        __builtin_amdgcn_s_setprio(0);
        if (doA) {
            asm volatile("s_waitcnt vmcnt(4)" ::: "memory");   // A(t+1)+B(t+1) resident
        } else if (doB) {
            asm volatile("s_waitcnt vmcnt(0)" ::: "memory");   // tail: drain all
        }
        if (doA || doB) {
            asm volatile("s_waitcnt lgkmcnt(0)" ::: "memory"); // my ds_reads done pre-barrier
            __builtin_amdgcn_s_barrier();
        }
    };

    // prologue: A(0)->buf0, B(0)->bA, A(1)->buf1 ; vmcnt(4) leaves A(1)
    {
        const unsigned short* pA_ = A2 + aoff_of(0);
#pragma unroll
        for (int it = 0; it < 4; ++it)
            load16_to_lds(pA_ + aTh[it], (char*)As[0] + it * 8192 + dst16);
        const unsigned short* bp = Bt2 + boff_of(0);
#pragma unroll
        for (int f = 0; f < 8; ++f)
            bA[f] = *reinterpret_cast<const short8*>(bp + bOff[f]);
        const unsigned short* qA_ = A2 + aoff_of(1);
#pragma unroll
        for (int it = 0; it < 4; ++it)
            load16_to_lds(qA_ + aTh[it], (char*)As[1] + it * 8192 + dst16);
    }
    asm volatile("s_waitcnt vmcnt(4)" ::: "memory");
    __builtin_amdgcn_s_barrier();

    // main loop: 7 x 6 tiles (t = 0..41), LDS buf period 3, reg buf period 2
#pragma unroll 1
    for (int tt = 0; tt < 7; ++tt) {
        const int t = tt * 6;
        tile(IC<0>{}, IC<0>{}, t + 0, true, true);
        tile(IC<1>{}, IC<1>{}, t + 1, true, true);
        tile(IC<2>{}, IC<0>{}, t + 2, true, true);
        tile(IC<0>{}, IC<1>{}, t + 3, true, true);
        tile(IC<1>{}, IC<0>{}, t + 4, true, true);
        tile(IC<2>{}, IC<1>{}, t + 5, true, true);
    }
    // tail t = 42..47
    tile(IC<0>{}, IC<0>{}, 42, true, true);
    tile(IC<1>{}, IC<1>{}, 43, true, true);
    tile(IC<2>{}, IC<0>{}, 44, true, true);
    tile(IC<0>{}, IC<1>{}, 45, true, true);    // stages A(47), loads B(46)
    tile(IC<1>{}, IC<0>{}, 46, false, true);   // loads B(47); vmcnt(0) at end
    tile(IC<2>{}, IC<1>{}, 47, false, false);  // pure compute

    // epilogue: bias + relu + quantize (RNE matches jnp.round)
    const int colBase = n0 + wc * 64 + (lane & 15);
    const int rowBase = m0 + wr * 64 + ((lane >> 4) << 2);
#pragma unroll
    for (int i = 0; i < 4; ++i) {
#pragma unroll
        for (int j = 0; j < 4; ++j) {
            int col = colBase + j * 16;
            float bv = bias[col];
#pragma unroll
            for (int r = 0; r < 4; ++r) {
                int row = rowBase + i * 16 + r;
                float y = acc[i][j][r] + bv;
                y = fmaxf(y, 0.0f);
                y = rintf(y * 65536.0f) * (1.0f / 65536.0f);
                out[(size_t)row * 1024 + col] = y;
            }
        }
    }
}

// ---------------- fallback (ws too small): naive fp32 ----------------
__global__ __launch_bounds__(256) void naive_kernel(const float* __restrict__ x,
                                                    const float* __restrict__ w,
                                                    const float* __restrict__ bias,
                                                    float* __restrict__ out) {
    int idx = blockIdx.x * 256 + threadIdx.x;
    int row = idx >> 10, col = idx & 1023;
    float s = bias[col];
    for (int k = 0; k < 1024; ++k)
        s += x[(size_t)row * 1024 + k] * w[(size_t)k * 1024 + col];
    s = fmaxf(s, 0.0f);
    out[idx] = rintf(s * 65536.0f) * (1.0f / 65536.0f);
}

extern "C" void kernel_launch(void* const* d_in, const int* in_sizes, int n_in,
                              void* d_out, int out_size, void* d_ws, size_t ws_size,
                              hipStream_t stream) {
    const float* x = (const float*)d_in[0];
    const float* w = (const float*)d_in[1];
    const float* b = (const float*)d_in[2];
    float* out = (float*)d_out;

    const size_t needA = (size_t)8192 * 2048 * 2;   // 32 MB
    const size_t needB = (size_t)1024 * 2048 * 2;   //  4 MB
    if (ws_size < needA + needB) {
        naive_kernel<<<(8192 * 1024) / 256, 256, 0, stream>>>(x, w, b, out);
        return;
    }
    unsigned short* A2  = (unsigned short*)d_ws;
    unsigned short* Bt2 = (unsigned short*)((char*)d_ws + needA);

    split_x_kernel<<<(8192 * 1024 / 8) / 256, 256, 0, stream>>>(x, A2);
    split_w_kernel<<<dim3(32, 32), dim3(32, 32), 0, stream>>>(w, Bt2);
    gemm_kernel<<<256, 512, 0, stream>>>(A2, Bt2, b, out);
}

// Round 9
// 190.366 us; speedup vs baseline: 1.0870x; 1.0870x over previous
//
#include <hip/hip_runtime.h>
#include <hip/hip_bf16.h>
#include <stdint.h>

// out = quantize(relu(x @ w + b)), x:8192x1024 f32 (fixed-point grid), w:1024x1024.
// 3-limb-product bf16 decomposition (y ~= xh*wh + xm*wh + xh*wl), virtual K'=3072.
// r9: ONE dispatch. r8 post-mortem: gemm reverted to r7 (64.4us, best). Totals
// show ~60us fixed non-gemm overhead across r2/r5/r7/r8 while splits compute to
// ~15us -> fuse split+gemm into a persistent kernel with a flag-based grid
// barrier (256 blocks x 144KB LDS = 1 block/CU, all co-resident by construction;
// device-scope release/acquire fences handle cross-XCD L2 non-coherence).
// GEMM = r7: 256x128 tile, BK=64, 8 waves 64x64, 3-deep LDS pipeline, 2 phase/
// tile, hoisted addresses, IC<> compile-time buffer idx, counted vmcnt(6),
// setprio MFMA, XOR bank swizzle (rule 21), bijective XCD swizzle (T1).

typedef __attribute__((ext_vector_type(8))) short short8;
typedef __attribute__((ext_vector_type(4))) float f32x4;
typedef __attribute__((ext_vector_type(8))) unsigned short us8;

template <int N> struct IC { static constexpr int v = N; };

#define SENT 0x5EED5EEDu

__device__ __forceinline__ unsigned short f32_to_bf16_rne(float f) {
    uint32_t u = __float_as_uint(f);
    uint32_t r = u + 0x7FFFu + ((u >> 16) & 1u);
    return (unsigned short)(r >> 16);
}
__device__ __forceinline__ float bf16_to_f32(unsigned short s) {
    return __uint_as_float(((uint32_t)s) << 16);
}

#define BM 256
#define BN 128
#define BK 64
#define NT 48   // 3 limb-product blocks x 16 sub-tiles of 64

__device__ __forceinline__ void load16_to_lds(const void* g, void* l) {
    __builtin_amdgcn_global_load_lds(
        (const __attribute__((address_space(1))) unsigned int*)g,
        (__attribute__((address_space(3))) unsigned int*)l,
        16, 0, 0);
}

__device__ __forceinline__ void rd4(short8* dst, const void* base, const int* offs) {
#pragma unroll
    for (int f = 0; f < 4; ++f)
        dst[f] = *reinterpret_cast<const short8*>((const char*)base + offs[f]);
}

__device__ __forceinline__ void mfma16(f32x4 (&acc)[4][4], const short8* af, const short8* bf) {
#pragma unroll
    for (int i = 0; i < 4; ++i)
#pragma unroll
        for (int j = 0; j < 4; ++j)
            acc[i][j] = __builtin_amdgcn_mfma_f32_16x16x32_bf16(af[i], bf[j], acc[i][j], 0, 0, 0);
}

__global__ __launch_bounds__(512, 2) void fused_kernel(const float* __restrict__ x,
                                                       const float* __restrict__ w,
                                                       const float* __restrict__ bias,
                                                       float* __restrict__ out,
                                                       unsigned short* __restrict__ A2,
                                                       unsigned short* __restrict__ Bt2,
                                                       unsigned int* __restrict__ flags) {
    __shared__ unsigned short As[3][BM * BK];   // 3 x 32 KB
    __shared__ unsigned short Bs[3][BN * BK];   // 3 x 16 KB  -> 144 KB total

    const int tid = threadIdx.x;
    const int bid = blockIdx.x;

    // ================= phase 1a: split x share (rows bid*32..+32) =================
    {
        const float* xs = x + (size_t)bid * 32 * 1024;
        unsigned short* Ad = A2 + (size_t)bid * 32 * 2048;
#pragma unroll 2
        for (int it = 0; it < 8; ++it) {
            int u = it * 512 + tid;            // 8-elem unit, 0..4095
            int e = u * 8;
            int row = e >> 10, col = e & 1023;
            float4 v0 = reinterpret_cast<const float4*>(xs)[2 * u];
            float4 v1 = reinterpret_cast<const float4*>(xs)[2 * u + 1];
            float vv[8] = {v0.x, v0.y, v0.z, v0.w, v1.x, v1.y, v1.z, v1.w};
            us8 h, m;
            unsigned short* hp = (unsigned short*)&h;
            unsigned short* mp = (unsigned short*)&m;
#pragma unroll
            for (int j = 0; j < 8; ++j) {
                float f = vv[j];
                unsigned short hb = f32_to_bf16_rne(f);
                float r1 = f - bf16_to_f32(hb);
                hp[j] = hb; mp[j] = f32_to_bf16_rne(r1);
            }
            size_t base = (size_t)row * 2048 + col;
            *reinterpret_cast<us8*>(&Ad[base])        = h;
            *reinterpret_cast<us8*>(&Ad[base + 1024]) = m;
        }
    }
    // ====== phase 1b: transpose+split 4 w-tiles (32x32) via padded LDS ======
    {
        float* T = (float*)As;                 // reuse LDS: 4*32*33*4B = 16.9 KB
        int tile = tid >> 7;                   // 0..3
        int sub  = tid & 127;
        int tx = sub & 31, ty = sub >> 5;      // ty 0..3
        int id = bid * 4 + tile;               // 0..1023
        int k0 = (id >> 5) * 32, n0w = (id & 31) * 32;
        float* Tt = T + tile * 32 * 33;
#pragma unroll
        for (int r = 0; r < 32; r += 4)
            Tt[(r + ty) * 33 + tx] = w[(size_t)(k0 + r + ty) * 1024 + (n0w + tx)];
        __syncthreads();
#pragma unroll
        for (int r = 0; r < 32; r += 4) {
            float f = Tt[tx * 33 + (r + ty)];  // = w[k0+tx][n0w+r+ty]
            unsigned short h = f32_to_bf16_rne(f);
            unsigned short l = f32_to_bf16_rne(f - bf16_to_f32(h));
            int n = n0w + r + ty, k = k0 + tx;
            Bt2[(size_t)n * 2048 + k]        = h;
            Bt2[(size_t)n * 2048 + 1024 + k] = l;
        }
    }
    // ================= grid barrier (all 256 blocks co-resident) =================
    __syncthreads();                           // drains vmem; LDS reuse safe below
    if (tid == 0) {
        __threadfence();                       // release: writeback to common point
        __hip_atomic_store(&flags[bid], SENT, __ATOMIC_RELEASE, __HIP_MEMORY_SCOPE_AGENT);
        for (int i = 0; i < 256; ++i) {
            while (__hip_atomic_load(&flags[i], __ATOMIC_RELAXED, __HIP_MEMORY_SCOPE_AGENT) != SENT)
                __builtin_amdgcn_s_sleep(2);
        }
        __threadfence();                       // acquire: invalidate stale caches
    }
    __syncthreads();

    // ========================== phase 2: gemm (r7) ==========================
    const int lane = tid & 63;
    const int wave = tid >> 6;
    const int wr = wave >> 1, wc = wave & 1;    // 4M x 2N waves, each 64x64 out

    const int wg  = (bid & 7) * 32 + (bid >> 3);
    const int bm = wg >> 3, bn = wg & 7;
    const int m0 = bm * BM, n0 = bn * BN;

    f32x4 acc[4][4];
#pragma unroll
    for (int i = 0; i < 4; ++i)
#pragma unroll
        for (int j = 0; j < 4; ++j) acc[i][j] = (f32x4)0.0f;

    int a0[4], a1[4], b0[4], b1[4];
    {
        const int ch0 = lane >> 4, ch1 = 4 + (lane >> 4);
#pragma unroll
        for (int f = 0; f < 4; ++f) {
            int ar = wr * 64 + f * 16 + (lane & 15);
            a0[f] = ar * 128 + ((ch0 ^ (ar & 7)) << 4);
            a1[f] = ar * 128 + ((ch1 ^ (ar & 7)) << 4);
            int br = wc * 64 + f * 16 + (lane & 15);
            b0[f] = br * 128 + ((ch0 ^ (br & 7)) << 4);
            b1[f] = br * 128 + ((ch1 ^ (br & 7)) << 4);
        }
    }
    int aTh[4], bTh[2];
#pragma unroll
    for (int it = 0; it < 4; ++it) {
        int c = it * 512 + tid, row = c >> 3, sw = (c & 7) ^ (row & 7);
        aTh[it] = (m0 + row) * 2048 + sw * 8;
    }
#pragma unroll
    for (int it = 0; it < 2; ++it) {
        int c = it * 512 + tid, row = c >> 3, sw = (c & 7) ^ (row & 7);
        bTh[it] = (n0 + row) * 2048 + sw * 8;
    }
    const int dst16 = tid * 16;

    auto aoff_of = [](int t) { int blk = t >> 4; return ((blk == 1) ? 1024 : 0) + (t & 15) * 64; };
    auto boff_of = [](int t) { int blk = t >> 4; return ((blk == 2) ? 1024 : 0) + (t & 15) * 64; };

    auto tile = [&](auto BC, auto NBC, int t, bool doStage) {
        constexpr int B  = decltype(BC)::v;
        constexpr int NB = decltype(NBC)::v;
        short8 af[4], bf[4];
        rd4(af, As[B], a0);
        rd4(bf, Bs[B], b0);
        if (doStage) {
            const unsigned short* pA_ = A2 + aoff_of(t + 2);
            load16_to_lds(pA_ + aTh[0], (char*)As[NB] + 0 * 8192 + dst16);
            load16_to_lds(pA_ + aTh[1], (char*)As[NB] + 1 * 8192 + dst16);
            load16_to_lds(pA_ + aTh[2], (char*)As[NB] + 2 * 8192 + dst16);
        }
        __builtin_amdgcn_s_barrier();
        __builtin_amdgcn_s_setprio(1);
        mfma16(acc, af, bf);
        __builtin_amdgcn_s_setprio(0);
        __builtin_amdgcn_s_barrier();
        rd4(af, As[B], a1);
        rd4(bf, Bs[B], b1);
        if (doStage) {
            const unsigned short* pA_ = A2 + aoff_of(t + 2);
            const unsigned short* pB_ = Bt2 + boff_of(t + 2);
            load16_to_lds(pA_ + aTh[3], (char*)As[NB] + 3 * 8192 + dst16);
            load16_to_lds(pB_ + bTh[0], (char*)Bs[NB] + 0 * 8192 + dst16);
            load16_to_lds(pB_ + bTh[1], (char*)Bs[NB] + 1 * 8192 + dst16);
        }
        __builtin_amdgcn_s_barrier();
        __builtin_amdgcn_s_setprio(1);
        mfma16(acc, af, bf);
        __builtin_amdgcn_s_setprio(0);
        asm volatile("s_waitcnt lgkmcnt(0)" ::: "memory");
    };

    // prologue: fully stage tiles 0 (buf0) then 1 (buf1)
    {
        const unsigned short* pA_ = A2 + aoff_of(0);
        const unsigned short* pB_ = Bt2 + boff_of(0);
        load16_to_lds(pA_ + aTh[0], (char*)As[0] + 0 * 8192 + dst16);
        load16_to_lds(pA_ + aTh[1], (char*)As[0] + 1 * 8192 + dst16);
        load16_to_lds(pA_ + aTh[2], (char*)As[0] + 2 * 8192 + dst16);
        load16_to_lds(pA_ + aTh[3], (char*)As[0] + 3 * 8192 + dst16);
        load16_to_lds(pB_ + bTh[0], (char*)Bs[0] + 0 * 8192 + dst16);
        load16_to_lds(pB_ + bTh[1], (char*)Bs[0] + 1 * 8192 + dst16);
        const unsigned short* qA_ = A2 + aoff_of(1);
        const unsigned short* qB_ = Bt2 + boff_of(1);
        load16_to_lds(qA_ + aTh[0], (char*)As[1] + 0 * 8192 + dst16);
        load16_to_lds(qA_ + aTh[1], (char*)As[1] + 1 * 8192 + dst16);
        load16_to_lds(qA_ + aTh[2], (char*)As[1] + 2 * 8192 + dst16);
        load16_to_lds(qA_ + aTh[3], (char*)As[1] + 3 * 8192 + dst16);
        load16_to_lds(qB_ + bTh[0], (char*)Bs[1] + 0 * 8192 + dst16);
        load16_to_lds(qB_ + bTh[1], (char*)Bs[1] + 1 * 8192 + dst16);
    }
    asm volatile("s_waitcnt vmcnt(6)" ::: "memory");   // tile 0 resident
    __builtin_amdgcn_s_barrier();

#pragma unroll 1
    for (int tt = 0; tt < 15; ++tt) {
        const int t = tt * 3;
        tile(IC<0>{}, IC<2>{}, t, true);
        asm volatile("s_waitcnt vmcnt(6)" ::: "memory");
        __builtin_amdgcn_s_barrier();
        tile(IC<1>{}, IC<0>{}, t + 1, true);
        asm volatile("s_waitcnt vmcnt(6)" ::: "memory");
        __builtin_amdgcn_s_barrier();
        tile(IC<2>{}, IC<1>{}, t + 2, true);
        asm volatile("s_waitcnt vmcnt(6)" ::: "memory");
        __builtin_amdgcn_s_barrier();
    }
    tile(IC<0>{}, IC<2>{}, 45, true);
    asm volatile("s_waitcnt vmcnt(6)" ::: "memory");
    __builtin_amdgcn_s_barrier();
    tile(IC<1>{}, IC<0>{}, 46, false);
    asm volatile("s_waitcnt vmcnt(0)" ::: "memory");
    __builtin_amdgcn_s_barrier();
    tile(IC<2>{}, IC<0>{}, 47, false);

    // epilogue: bias + relu + quantize (RNE matches jnp.round)
    const int colBase = n0 + wc * 64 + (lane & 15);
    const int rowBase = m0 + wr * 64 + ((lane >> 4) << 2);
#pragma unroll
    for (int i = 0; i < 4; ++i) {
#pragma unroll
        for (int j = 0; j < 4; ++j) {
            int col = colBase + j * 16;
            float bv = bias[col];
#pragma unroll
            for (int r = 0; r < 4; ++r) {
                int row = rowBase + i * 16 + r;
                float y = acc[i][j][r] + bv;
                y = fmaxf(y, 0.0f);
                y = rintf(y * 65536.0f) * (1.0f / 65536.0f);
                out[(size_t)row * 1024 + col] = y;
            }
        }
    }
}

// ---------------- fallback (ws too small): naive fp32 ----------------
__global__ __launch_bounds__(256) void naive_kernel(const float* __restrict__ x,
                                                    const float* __restrict__ w,
                                                    const float* __restrict__ bias,
                                                    float* __restrict__ out) {
    int idx = blockIdx.x * 256 + threadIdx.x;
    int row = idx >> 10, col = idx & 1023;
    float s = bias[col];
    for (int k = 0; k < 1024; ++k)
        s += x[(size_t)row * 1024 + k] * w[(size_t)k * 1024 + col];
    s = fmaxf(s, 0.0f);
    out[idx] = rintf(s * 65536.0f) * (1.0f / 65536.0f);
}

extern "C" void kernel_launch(void* const* d_in, const int* in_sizes, int n_in,
                              void* d_out, int out_size, void* d_ws, size_t ws_size,
                              hipStream_t stream) {
    const float* x = (const float*)d_in[0];
    const float* w = (const float*)d_in[1];
    const float* b = (const float*)d_in[2];
    float* out = (float*)d_out;

    const size_t needA = (size_t)8192 * 2048 * 2;   // 32 MB
    const size_t needB = (size_t)1024 * 2048 * 2;   //  4 MB
    const size_t needF = 256 * sizeof(unsigned int);
    if (ws_size < needA + needB + needF) {
        naive_kernel<<<(8192 * 1024) / 256, 256, 0, stream>>>(x, w, b, out);
        return;
    }
    unsigned short* A2  = (unsigned short*)d_ws;
    unsigned short* Bt2 = (unsigned short*)((char*)d_ws + needA);
    unsigned int* flags = (unsigned int*)((char*)d_ws + needA + needB);

    fused_kernel<<<256, 512, 0, stream>>>(x, w, b, out, A2, Bt2, flags);
}

// Round 10
// 179.565 us; speedup vs baseline: 1.1524x; 1.0602x over previous
//
#include <hip/hip_runtime.h>
#include <hip/hip_bf16.h>
#include <stdint.h>

// out = quantize(relu(x @ w + b)), x:8192x1024 f32 (fixed-point grid), w:1024x1024.
// 3-limb-product bf16 decomposition: y ~= xh*wh + xm*wh + xh*wl (K'=3072).
// r10: (1) grid-barrier spin PARALLELIZED (r9 post-mortem: serial 256-flag scan
// by tid0 = ~48us of cross-die load latency; now threads 0..255 poll one flag
// each). (2) limb-structured register reuse in the gemm: K reordered sub-major
// (16 super-steps x {blk0=ah*bh, blk1=am*bh, blk2=ah*bl}); ah,bh,am fragments
// cached in regs -> LDS reads 384->256 KB per 3 tiles (r7 was LDS-read-bound),
// staging 144->96 KB, LDS = 4 single-buffered slots (96 KB) recycled in place.
// Kept: 256x128 tile, 8 waves 64x64, hoisted addresses, XOR swizzle (rule 21),
// bijective XCD swizzle, setprio on MFMA, gload_lds width-16.

typedef __attribute__((ext_vector_type(8))) short short8;
typedef __attribute__((ext_vector_type(4))) float f32x4;
typedef __attribute__((ext_vector_type(8))) unsigned short us8;

#define SENT 0x5EED5EEDu

__device__ __forceinline__ unsigned short f32_to_bf16_rne(float f) {
    uint32_t u = __float_as_uint(f);
    uint32_t r = u + 0x7FFFu + ((u >> 16) & 1u);
    return (unsigned short)(r >> 16);
}
__device__ __forceinline__ float bf16_to_f32(unsigned short s) {
    return __uint_as_float(((uint32_t)s) << 16);
}

#define BM 256
#define BN 128
#define BK 64

__device__ __forceinline__ void load16_to_lds(const void* g, void* l) {
    __builtin_amdgcn_global_load_lds(
        (const __attribute__((address_space(1))) unsigned int*)g,
        (__attribute__((address_space(3))) unsigned int*)l,
        16, 0, 0);
}

__device__ __forceinline__ void rd4(short8* dst, const void* base, const int* offs) {
#pragma unroll
    for (int f = 0; f < 4; ++f)
        dst[f] = *reinterpret_cast<const short8*>((const char*)base + offs[f]);
}

__device__ __forceinline__ void mfma16(f32x4 (&acc)[4][4], const short8* af, const short8* bf) {
#pragma unroll
    for (int i = 0; i < 4; ++i)
#pragma unroll
        for (int j = 0; j < 4; ++j)
            acc[i][j] = __builtin_amdgcn_mfma_f32_16x16x32_bf16(af[i], bf[j], acc[i][j], 0, 0, 0);
}

__global__ __launch_bounds__(512, 2) void fused_kernel(const float* __restrict__ x,
                                                       const float* __restrict__ w,
                                                       const float* __restrict__ bias,
                                                       float* __restrict__ out,
                                                       unsigned short* __restrict__ A2,
                                                       unsigned short* __restrict__ Bt2,
                                                       unsigned int* __restrict__ flags) {
    // 4 single-buffered LDS slots, recycled in place each super-step (96 KB)
    __shared__ unsigned short Ah[BM * BK];    // 32 KB  (xh limb tile)
    __shared__ unsigned short Am_[BM * BK];   // 32 KB  (xm limb tile)
    __shared__ unsigned short Bh_[BN * BK];   // 16 KB  (wh limb tile)
    __shared__ unsigned short Bl_[BN * BK];   // 16 KB  (wl limb tile)

    const int tid = threadIdx.x;
    const int bid = blockIdx.x;

    // ================= phase 1a: split x share (rows bid*32..+32) =================
    {
        const float* xs = x + (size_t)bid * 32 * 1024;
        unsigned short* Ad = A2 + (size_t)bid * 32 * 2048;
#pragma unroll 2
        for (int it = 0; it < 8; ++it) {
            int u = it * 512 + tid;            // 8-elem unit, 0..4095
            int e = u * 8;
            int row = e >> 10, col = e & 1023;
            float4 v0 = reinterpret_cast<const float4*>(xs)[2 * u];
            float4 v1 = reinterpret_cast<const float4*>(xs)[2 * u + 1];
            float vv[8] = {v0.x, v0.y, v0.z, v0.w, v1.x, v1.y, v1.z, v1.w};
            us8 h, m;
            unsigned short* hp = (unsigned short*)&h;
            unsigned short* mp = (unsigned short*)&m;
#pragma unroll
            for (int j = 0; j < 8; ++j) {
                float f = vv[j];
                unsigned short hb = f32_to_bf16_rne(f);
                float r1 = f - bf16_to_f32(hb);
                hp[j] = hb; mp[j] = f32_to_bf16_rne(r1);
            }
            size_t base = (size_t)row * 2048 + col;
            *reinterpret_cast<us8*>(&Ad[base])        = h;
            *reinterpret_cast<us8*>(&Ad[base + 1024]) = m;
        }
    }
    // ====== phase 1b: transpose+split 4 w-tiles (32x32) via padded LDS ======
    {
        float* T = (float*)Ah;                 // reuse LDS: 4*32*33*4B = 16.9 KB
        int tile = tid >> 7;                   // 0..3
        int sub  = tid & 127;
        int tx = sub & 31, ty = sub >> 5;      // ty 0..3
        int id = bid * 4 + tile;               // 0..1023
        int k0 = (id >> 5) * 32, n0w = (id & 31) * 32;
        float* Tt = T + tile * 32 * 33;
#pragma unroll
        for (int r = 0; r < 32; r += 4)
            Tt[(r + ty) * 33 + tx] = w[(size_t)(k0 + r + ty) * 1024 + (n0w + tx)];
        __syncthreads();
#pragma unroll
        for (int r = 0; r < 32; r += 4) {
            float f = Tt[tx * 33 + (r + ty)];  // = w[k0+tx][n0w+r+ty]
            unsigned short h = f32_to_bf16_rne(f);
            unsigned short l = f32_to_bf16_rne(f - bf16_to_f32(h));
            int n = n0w + r + ty, k = k0 + tx;
            Bt2[(size_t)n * 2048 + k]        = h;
            Bt2[(size_t)n * 2048 + 1024 + k] = l;
        }
    }
    // ============ grid barrier (parallel spin; 256 blocks co-resident) ============
    __syncthreads();                           // all stores retired (vmcnt drain)
    if (tid == 0) {
        __threadfence();                       // release
        __hip_atomic_store(&flags[bid], SENT, __ATOMIC_RELEASE, __HIP_MEMORY_SCOPE_AGENT);
    }
    if (tid < 256) {                           // each thread polls ONE flag
        while (__hip_atomic_load(&flags[tid], __ATOMIC_RELAXED, __HIP_MEMORY_SCOPE_AGENT) != SENT)
            __builtin_amdgcn_s_sleep(2);
    }
    __syncthreads();
    __threadfence();                           // acquire (all threads)

    // ========================== phase 2: gemm ==========================
    const int lane = tid & 63;
    const int wave = tid >> 6;
    const int wr = wave >> 1, wc = wave & 1;    // 4M x 2N waves, each 64x64 out

    const int wg  = (bid & 7) * 32 + (bid >> 3);
    const int bm = wg >> 3, bn = wg & 7;
    const int m0 = bm * BM, n0 = bn * BN;

    f32x4 acc[4][4];
#pragma unroll
    for (int i = 0; i < 4; ++i)
#pragma unroll
        for (int j = 0; j < 4; ++j) acc[i][j] = (f32x4)0.0f;

    // hoisted ds_read byte offsets (slot-relative)
    int a0[4], a1[4], b0[4], b1[4];
    {
        const int ch0 = lane >> 4, ch1 = 4 + (lane >> 4);
#pragma unroll
        for (int f = 0; f < 4; ++f) {
            int ar = wr * 64 + f * 16 + (lane & 15);
            a0[f] = ar * 128 + ((ch0 ^ (ar & 7)) << 4);
            a1[f] = ar * 128 + ((ch1 ^ (ar & 7)) << 4);
            int br = wc * 64 + f * 16 + (lane & 15);
            b0[f] = br * 128 + ((ch0 ^ (br & 7)) << 4);
            b1[f] = br * 128 + ((ch1 ^ (br & 7)) << 4);
        }
    }
    // hoisted stage offsets (element offsets; uniform column base added per step)
    int aTh[4], bTh[2];
#pragma unroll
    for (int it = 0; it < 4; ++it) {
        int c = it * 512 + tid, row = c >> 3, sw = (c & 7) ^ (row & 7);
        aTh[it] = (m0 + row) * 2048 + sw * 8;
    }
#pragma unroll
    for (int it = 0; it < 2; ++it) {
        int c = it * 512 + tid, row = c >> 3, sw = (c & 7) ^ (row & 7);
        bTh[it] = (n0 + row) * 2048 + sw * 8;
    }
    const int dst16 = tid * 16;

    auto stageAh = [&](int g) {
        const unsigned short* p = A2 + g * 64;
#pragma unroll
        for (int it = 0; it < 4; ++it)
            load16_to_lds(p + aTh[it], (char*)Ah + it * 8192 + dst16);
    };
    auto stageAm = [&](int g) {
        const unsigned short* p = A2 + 1024 + g * 64;
#pragma unroll
        for (int it = 0; it < 4; ++it)
            load16_to_lds(p + aTh[it], (char*)Am_ + it * 8192 + dst16);
    };
    auto stageBh = [&](int g) {
        const unsigned short* p = Bt2 + g * 64;
#pragma unroll
        for (int it = 0; it < 2; ++it)
            load16_to_lds(p + bTh[it], (char*)Bh_ + it * 8192 + dst16);
    };
    auto stageBl = [&](int g) {
        const unsigned short* p = Bt2 + 1024 + g * 64;
#pragma unroll
        for (int it = 0; it < 2; ++it)
            load16_to_lds(p + bTh[it], (char*)Bl_ + it * 8192 + dst16);
    };

    // prologue: stage generation 0 into all 4 slots
    stageAh(0); stageAm(0); stageBh(0); stageBl(0);

    // 16 super-steps; per step 3 limb-product K-tiles sharing cached fragments
#pragma unroll 1
    for (int g = 0; g < 16; ++g) {
        asm volatile("s_waitcnt vmcnt(0)" ::: "memory");   // gen-g stage loads done
        __builtin_amdgcn_s_barrier();                      // B1: all waves -> slots valid
        short8 ah[8], bh[8], am[8];
        rd4(ah,     Ah,  a0); rd4(ah + 4, Ah,  a1);
        rd4(bh,     Bh_, b0); rd4(bh + 4, Bh_, b1);
        rd4(am,     Am_, a0); rd4(am + 4, Am_, a1);
        asm volatile("s_waitcnt lgkmcnt(0)" ::: "memory"); // my reads retired
        __builtin_amdgcn_s_barrier();                      // B2: Ah/Bh/Am slots free
        const bool st = (g < 15);
        if (st) { stageAh(g + 1); stageBh(g + 1); stageAm(g + 1); }  // 10 loads
        __builtin_amdgcn_s_setprio(1);
        // blk0: xh * wh
        mfma16(acc, &ah[0], &bh[0]);
        mfma16(acc, &ah[4], &bh[4]);
        __builtin_amdgcn_s_setprio(0);
        short8 bl[8];
        rd4(bl, Bl_, b0); rd4(bl + 4, Bl_, b1);            // Bl(g) (valid since B1)
        __builtin_amdgcn_s_setprio(1);
        // blk1: xm * wh (bh reused from regs)
        mfma16(acc, &am[0], &bh[0]);
        mfma16(acc, &am[4], &bh[4]);
        __builtin_amdgcn_s_setprio(0);
        asm volatile("s_waitcnt lgkmcnt(0)" ::: "memory"); // bl reads retired
        __builtin_amdgcn_s_barrier();                      // B3: Bl slot free
        if (st) stageBl(g + 1);                            // 2 loads
        __builtin_amdgcn_s_setprio(1);
        // blk2: xh * wl (ah reused from regs)
        mfma16(acc, &ah[0], &bl[0]);
        mfma16(acc, &ah[4], &bl[4]);
        __builtin_amdgcn_s_setprio(0);
    }

    // epilogue: bias + relu + quantize (RNE matches jnp.round)
    const int colBase = n0 + wc * 64 + (lane & 15);
    const int rowBase = m0 + wr * 64 + ((lane >> 4) << 2);
#pragma unroll
    for (int i = 0; i < 4; ++i) {
#pragma unroll
        for (int j = 0; j < 4; ++j) {
            int col = colBase + j * 16;
            float bv = bias[col];
#pragma unroll
            for (int r = 0; r < 4; ++r) {
                int row = rowBase + i * 16 + r;
                float y = acc[i][j][r] + bv;
                y = fmaxf(y, 0.0f);
                y = rintf(y * 65536.0f) * (1.0f / 65536.0f);
                out[(size_t)row * 1024 + col] = y;
            }
        }
    }
}

// ---------------- fallback (ws too small): naive fp32 ----------------
__global__ __launch_bounds__(256) void naive_kernel(const float* __restrict__ x,
                                                    const float* __restrict__ w,
                                                    const float* __restrict__ bias,
                                                    float* __restrict__ out) {
    int idx = blockIdx.x * 256 + threadIdx.x;
    int row = idx >> 10, col = idx & 1023;
    float s = bias[col];
    for (int k = 0; k < 1024; ++k)
        s += x[(size_t)row * 1024 + k] * w[(size_t)k * 1024 + col];
    s = fmaxf(s, 0.0f);
    out[idx] = rintf(s * 65536.0f) * (1.0f / 65536.0f);
}

extern "C" void kernel_launch(void* const* d_in, const int* in_sizes, int n_in,
                              void* d_out, int out_size, void* d_ws, size_t ws_size,
                              hipStream_t stream) {
    const float* x = (const float*)d_in[0];
    const float* w = (const float*)d_in[1];
    const float* b = (const float*)d_in[2];
    float* out = (float*)d_out;

    const size_t needA = (size_t)8192 * 2048 * 2;   // 32 MB
    const size_t needB = (size_t)1024 * 2048 * 2;   //  4 MB
    const size_t needF = 256 * sizeof(unsigned int);
    if (ws_size < needA + needB + needF) {
        naive_kernel<<<(8192 * 1024) / 256, 256, 0, stream>>>(x, w, b, out);
        return;
    }
    unsigned short* A2  = (unsigned short*)d_ws;
    unsigned short* Bt2 = (unsigned short*)((char*)d_ws + needA);
    unsigned int* flags = (unsigned int*)((char*)d_ws + needA + needB);

    fused_kernel<<<256, 512, 0, stream>>>(x, w, b, out, A2, Bt2, flags);
}